// Round 3
// baseline (295.083 us; speedup 1.0000x reference)
//
#include <hip/hip_runtime.h>

#define DD 160

// ============ K1: X-pass ============
// in/tg: raw [B][160][160][160]. out xb: 5 channels [ch][b][x'][y][z] (z contig).
// Thread = (chunk c, b, y, z); slides a window along x (stride s, dilation 2).
// All tap loads & stores coalesced (lane-consecutive z).
__global__ __launch_bounds__(256) void k1_kernel(
    const float* __restrict__ in, const float* __restrict__ tg,
    float* __restrict__ xb, int B, int n, int k, int s, int CL) {
    const long XS = (long)DD * DD;
    const long P  = (long)B * DD * DD;
    const int  CC = (n + CL - 1) / CL;
    long t = (long)blockIdx.x * 256 + threadIdx.x;
    if (t >= P * CC) return;
    long p = t % P;
    int  c = (int)(t / P);
    // p = (b*160 + y)*160 + z  → addresses linear in p for fixed (b,x)
    int b = (int)(p / (DD * DD));
    long yz = p % (DD * DD);
    const float* ia = in + (long)b * DD * XS + yz;
    const float* ta = tg + (long)b * DD * XS + yz;
    const long CH = (long)B * n * XS;
    float* ob = xb + (long)b * n * XS + yz;

    int x0 = c * CL, x1 = min(n, x0 + CL);
    float s0 = 0.f, s1 = 0.f, s2 = 0.f, s3 = 0.f, s4 = 0.f;
    int xs = x0 * s;
    for (int i = 0; i < k; ++i) {
        float a = ia[(long)(xs + 2 * i) * XS];
        float bb = ta[(long)(xs + 2 * i) * XS];
        s0 += a; s1 += bb; s2 += a * a; s3 += bb * bb; s4 += a * bb;
    }
    long o0 = (long)x0 * XS;
    ob[o0] = s0; ob[o0 + CH] = s1; ob[o0 + 2 * CH] = s2; ob[o0 + 3 * CH] = s3; ob[o0 + 4 * CH] = s4;
    for (int xp = x0 + 1; xp < x1; ++xp) {
        if ((s & 1) == 0) {                      // taps keep parity: remove/add s/2
            int o = (xp - 1) * s;
            for (int j = 0; j < (s >> 1); ++j) {
                float a = ia[(long)(o + 2 * j) * XS];
                float bb = ta[(long)(o + 2 * j) * XS];
                s0 -= a; s1 -= bb; s2 -= a * a; s3 -= bb * bb; s4 -= a * bb;
                a  = ia[(long)(o + 2 * k + 2 * j) * XS];
                bb = ta[(long)(o + 2 * k + 2 * j) * XS];
                s0 += a; s1 += bb; s2 += a * a; s3 += bb * bb; s4 += a * bb;
            }
        } else {                                 // s odd: parity flips, recompute
            s0 = s1 = s2 = s3 = s4 = 0.f;
            int st = xp * s;
            for (int i = 0; i < k; ++i) {
                float a = ia[(long)(st + 2 * i) * XS];
                float bb = ta[(long)(st + 2 * i) * XS];
                s0 += a; s1 += bb; s2 += a * a; s3 += bb * bb; s4 += a * bb;
            }
        }
        long oo = (long)xp * XS;
        ob[oo] = s0; ob[oo + CH] = s1; ob[oo + 2 * CH] = s2; ob[oo + 3 * CH] = s3; ob[oo + 4 * CH] = s4;
    }
}

// ============ K2: Y-pass ============
// src xb [ch][b][x'][y][z] → dst yb [ch][b][x'][y'][z]. One channel per thread.
__global__ __launch_bounds__(256) void k2_kernel(
    const float* __restrict__ src, float* __restrict__ dst,
    int B, int n, int k, int s, int CL) {
    const long XS = (long)DD * DD;
    const long CH = (long)B * n * XS;
    const long CH3 = (long)B * n * n * DD;
    const long Q  = 5L * B * n * DD;
    const int  CC = (n + CL - 1) / CL;
    long t = (long)blockIdx.x * 256 + threadIdx.x;
    if (t >= Q * CC) return;
    long q = t % Q;
    int  c = (int)(t / Q);
    int z = (int)(q % DD); long r = q / DD;
    int xp = (int)(r % n); r /= n;
    int b  = (int)(r % B);
    int ch = (int)(r / B);
    const float* sp = src + ch * CH + (long)(b * n + xp) * XS + z;
    float* dp = dst + ch * CH3 + (long)(b * n + xp) * n * DD + z;

    int y0 = c * CL, y1 = min(n, y0 + CL);
    float w = 0.f;
    int ys = y0 * s;
    for (int i = 0; i < k; ++i) w += sp[(long)(ys + 2 * i) * DD];
    dp[(long)y0 * DD] = w;
    for (int yp = y0 + 1; yp < y1; ++yp) {
        if ((s & 1) == 0) {
            int o = (yp - 1) * s;
            for (int j = 0; j < (s >> 1); ++j) {
                w -= sp[(long)(o + 2 * j) * DD];
                w += sp[(long)(o + 2 * k + 2 * j) * DD];
            }
        } else {
            w = 0.f;
            int st = yp * s;
            for (int i = 0; i < k; ++i) w += sp[(long)(st + 2 * i) * DD];
        }
        dp[(long)yp * DD] = w;
    }
}

// ============ K3: Z-pass + LNCC + reduction ============
// yb [ch][b][x'][y'][z=160]; one wave per row (b,x',y'): parity prefix-scan
// along z per channel, window sums = 2 LDS reads, LNCC, block reduce, atomic.
__global__ __launch_bounds__(256) void k3_kernel(
    const float* __restrict__ yb, float* __restrict__ acc,
    int B, int n, int k, int s, float numel) {
    __shared__ float S[4][5][162];
    __shared__ float wsum[4];
    const int wid = threadIdx.x >> 6, lane = threadIdx.x & 63;
    const long R3 = (long)B * n * n;
    const long CH3 = R3 * DD;
    const long row = (long)blockIdx.x * 4 + wid;
    const bool active = row < R3;
    float* Sw = &S[wid][0][0];
    float v = 0.f;
    if (active) {
        for (int ch = 0; ch < 5; ++ch) {
            const float* pp = yb + ch * CH3 + row * DD;
            float v0 = pp[lane], v1 = pp[lane + 64];
            float v2 = (lane < 32) ? pp[lane + 128] : 0.f;
#pragma unroll
            for (int o = 2; o <= 32; o <<= 1) {
                float t0 = __shfl_up(v0, o);
                float t1 = __shfl_up(v1, o);
                float t2 = __shfl_up(v2, o);
                if (lane >= o) { v0 += t0; v1 += t1; v2 += t2; }
            }
            float c1 = __shfl(v0, 62 + (lane & 1)); v1 += c1;
            float c2 = __shfl(v1, 62 + (lane & 1)); v2 += c2;
            float* outp = Sw + ch * 162;
            if (lane < 2) outp[lane] = 0.f;
            outp[lane + 2]  = v0;
            outp[lane + 66] = v1;
            if (lane < 32) outp[lane + 130] = v2;
        }
        for (int t = lane; t < n; t += 64) {
            int lo = t * s, hi = lo + 2 * k;
            float a0 = Sw[0 * 162 + hi] - Sw[0 * 162 + lo];
            float a1 = Sw[1 * 162 + hi] - Sw[1 * 162 + lo];
            float a2 = Sw[2 * 162 + hi] - Sw[2 * 162 + lo];
            float a3 = Sw[3 * 162 + hi] - Sw[3 * 162 + lo];
            float a4 = Sw[4 * 162 + hi] - Sw[4 * 162 + lo];
            float xm = a0 / numel, ym = a1 / numel;
            float cross = a4 - ym * a0 - xm * a1 + ym * xm * numel;
            float xvar  = a2 - 2.f * xm * a0 + xm * xm * numel;
            float yvar  = a3 - 2.f * ym * a1 + ym * ym * numel;
            v += cross * cross / (xvar * yvar + 1e-5f);
        }
    }
    for (int o = 32; o > 0; o >>= 1) v += __shfl_down(v, o, 64);
    if (lane == 0) wsum[wid] = v;
    __syncthreads();
    if (threadIdx.x == 0) atomicAdd(acc, wsum[0] + wsum[1] + wsum[2] + wsum[3]);
}

__global__ void finalize_kernel(const float* __restrict__ acc, float* __restrict__ out,
                                float c0, float c1, float c2,
                                float w0, float w1, float w2) {
    if (threadIdx.x == 0 && blockIdx.x == 0) {
        out[0] = w0 * (1.f - acc[0] / c0) +
                 w1 * (1.f - acc[1] / c1) +
                 w2 * (1.f - acc[2] / c2);
    }
}

extern "C" void kernel_launch(void* const* d_in, const int* in_sizes, int n_in,
                              void* d_out, int out_size, void* d_ws, size_t ws_size,
                              hipStream_t stream) {
    const float* input  = (const float*)d_in[0];
    const float* target = (const float*)d_in[1];
    float* out = (float*)d_out;

    const int NS[3]  = {71, 25, 9};
    const int KS[3]  = {10, 20, 40};
    const int SS[3]  = {2, 5, 10};
    const int CL1[3] = {9, 5, 3};   // x'-chunk per thread
    const int CL2[3] = {9, 5, 3};   // y'-chunk per thread

    char* ws = (char*)d_ws;
    float* acc = (float*)ws;
    const size_t accPad = 256;

    const size_t xbF = 5ull * 2 * 71 * DD * DD;       // 18,176,000 floats (scale-0 max)
    const size_t ybF = 5ull * 2 * 71 * 71 * DD;       //  8,065,600 floats
    const size_t fullNeed = accPad + (xbF + ybF) * sizeof(float);   // ~105 MB
    const int NB = (ws_size >= fullNeed) ? 2 : 1;

    float* xb = (float*)(ws + accPad);
    float* yb = xb + 5ull * NB * 71 * DD * DD;

    hipMemsetAsync(acc, 0, 3 * sizeof(float), stream);

    for (int b0 = 0; b0 < 2; b0 += NB) {
        const float* ip = input  + (size_t)b0 * DD * DD * DD;
        const float* tp = target + (size_t)b0 * DD * DD * DD;
        for (int sc = 0; sc < 3; ++sc) {
            const int n = NS[sc], k = KS[sc], s = SS[sc];
            const long P = (long)NB * DD * DD;
            const long t1 = P * ((n + CL1[sc] - 1) / CL1[sc]);
            k1_kernel<<<dim3((unsigned)((t1 + 255) / 256)), dim3(256), 0, stream>>>(
                ip, tp, xb, NB, n, k, s, CL1[sc]);
            const long Q = 5L * NB * n * DD;
            const long t2 = Q * ((n + CL2[sc] - 1) / CL2[sc]);
            k2_kernel<<<dim3((unsigned)((t2 + 255) / 256)), dim3(256), 0, stream>>>(
                xb, yb, NB, n, k, s, CL2[sc]);
            const long R3 = (long)NB * n * n;
            k3_kernel<<<dim3((unsigned)((R3 + 3) / 4)), dim3(256), 0, stream>>>(
                yb, acc + sc, NB, n, k, s, (float)k * (float)k * (float)k);
        }
    }
    finalize_kernel<<<dim3(1), dim3(64), 0, stream>>>(
        acc, out,
        2.f * NS[0] * NS[0] * NS[0],
        2.f * NS[1] * NS[1] * NS[1],
        2.f * NS[2] * NS[2] * NS[2],
        0.1f, 0.3f, 0.6f);
}

// Round 4
// 231.017 us; speedup vs baseline: 1.2773x; 1.2773x over previous
//
#include <hip/hip_runtime.h>

#define DD 160

// ============ K1: X-pass (templated) ============
// in/tg raw [B][160][160][160] -> xb 5 channels [ch][b][x'][y][z].
// Thread = (chunk, chain, b, y, z); slides window along x.
// NCH: parity chains (2 for odd S, else 1). Slide step NCH*S is always even
// -> remove/add R = NCH*S/2 taps, never recompute.
template<int N, int K, int S, int NCH, int CL>
__global__ __launch_bounds__(256) void k1t(
    const float* __restrict__ in, const float* __restrict__ tg,
    float* __restrict__ xb, int B) {
    const long XS = (long)DD * DD;
    const long P  = (long)B * XS;
    constexpr int NPC0 = (N + NCH - 1) / NCH;
    constexpr int CC   = (NPC0 + CL - 1) / CL;
    constexpr int R    = (NCH * S) / 2;
    long t = (long)blockIdx.x * 256 + threadIdx.x;
    if (t >= P * NCH * CC) return;
    long p = t % P;
    int  r = (int)(t / P);
    int chain  = r % NCH;
    int cchunk = r / NCH;
    int b = (int)(p / XS);
    long yz = p % XS;
    const float* ia = in + (long)b * DD * XS + yz;
    const float* ta = tg + (long)b * DD * XS + yz;
    const long CH = (long)B * N * XS;
    float* ob = xb + (long)b * N * XS + yz;

    const int npc = (N - chain + NCH - 1) / NCH;   // outputs in this chain
    int j0 = cchunk * CL;
    if (j0 >= npc) return;
    int xp = chain + j0 * NCH;
    int x0 = xp * S;
    float s0 = 0.f, s1 = 0.f, s2 = 0.f, s3 = 0.f, s4 = 0.f;
#pragma unroll
    for (int i = 0; i < K; ++i) {
        float a = ia[(long)(x0 + 2 * i) * XS];
        float c = ta[(long)(x0 + 2 * i) * XS];
        s0 += a; s1 += c; s2 += a * a; s3 += c * c; s4 += a * c;
    }
    {
        long oo = (long)xp * XS;
        ob[oo] = s0; ob[oo + CH] = s1; ob[oo + 2 * CH] = s2;
        ob[oo + 3 * CH] = s3; ob[oo + 4 * CH] = s4;
    }
#pragma unroll
    for (int q = 1; q < CL; ++q) {
        if (j0 + q >= npc) break;
#pragma unroll
        for (int j = 0; j < R; ++j) {
            float a = ia[(long)(x0 + 2 * j) * XS];
            float c = ta[(long)(x0 + 2 * j) * XS];
            s0 -= a; s1 -= c; s2 -= a * a; s3 -= c * c; s4 -= a * c;
            a = ia[(long)(x0 + 2 * K + 2 * j) * XS];
            c = ta[(long)(x0 + 2 * K + 2 * j) * XS];
            s0 += a; s1 += c; s2 += a * a; s3 += c * c; s4 += a * c;
        }
        xp += NCH;
        x0 += NCH * S;
        long oo = (long)xp * XS;
        ob[oo] = s0; ob[oo + CH] = s1; ob[oo + 2 * CH] = s2;
        ob[oo + 3 * CH] = s3; ob[oo + 4 * CH] = s4;
    }
}

// ============ K2: Y-pass (templated) ============
// xb [ch][b][x'][y][z] -> yb [ch][b][x'][y'][z]; one channel per thread.
template<int N, int K, int S, int NCH, int CL>
__global__ __launch_bounds__(256) void k2t(
    const float* __restrict__ src, float* __restrict__ dst, int B) {
    const long XS  = (long)DD * DD;
    const long CH  = (long)B * N * XS;
    const long CH3 = (long)B * N * N * DD;
    const long Q   = 5L * B * N * DD;
    constexpr int NPC0 = (N + NCH - 1) / NCH;
    constexpr int CC   = (NPC0 + CL - 1) / CL;
    constexpr int R    = (NCH * S) / 2;
    long t = (long)blockIdx.x * 256 + threadIdx.x;
    if (t >= Q * NCH * CC) return;
    long q = t % Q;
    int  r = (int)(t / Q);
    int chain  = r % NCH;
    int cchunk = r / NCH;
    int z = (int)(q % DD); long rr = q / DD;
    int xp = (int)(rr % N); rr /= N;
    int b  = (int)(rr % B);
    int ch = (int)(rr / B);
    const float* sp = src + ch * CH + ((long)b * N + xp) * XS + z;
    float* dp = dst + ch * CH3 + ((long)b * N + xp) * (long)N * DD + z;

    const int npc = (N - chain + NCH - 1) / NCH;
    int j0 = cchunk * CL;
    if (j0 >= npc) return;
    int yp = chain + j0 * NCH;
    int y0 = yp * S;
    float w = 0.f;
#pragma unroll
    for (int i = 0; i < K; ++i) w += sp[(long)(y0 + 2 * i) * DD];
    dp[(long)yp * DD] = w;
#pragma unroll
    for (int qq = 1; qq < CL; ++qq) {
        if (j0 + qq >= npc) break;
#pragma unroll
        for (int j = 0; j < R; ++j) {
            w -= sp[(long)(y0 + 2 * j) * DD];
            w += sp[(long)(y0 + 2 * K + 2 * j) * DD];
        }
        yp += NCH;
        y0 += NCH * S;
        dp[(long)yp * DD] = w;
    }
}

// ============ K3: Z-pass + LNCC + reduction (templated) ============
template<int N, int K, int S>
__global__ __launch_bounds__(256) void k3t(
    const float* __restrict__ yb, float* __restrict__ acc, int B) {
    constexpr float numel = (float)K * K * K;
    __shared__ float Sm[4][5][162];
    __shared__ float wsum[4];
    const int wid = threadIdx.x >> 6, lane = threadIdx.x & 63;
    const long R3  = (long)B * N * N;
    const long CH3 = R3 * DD;
    const long row = (long)blockIdx.x * 4 + wid;
    float* Sw = &Sm[wid][0][0];
    float v = 0.f;
    if (row < R3) {
        for (int ch = 0; ch < 5; ++ch) {
            const float* pp = yb + ch * CH3 + row * DD;
            float v0 = pp[lane], v1 = pp[lane + 64];
            float v2 = (lane < 32) ? pp[lane + 128] : 0.f;
#pragma unroll
            for (int o = 2; o <= 32; o <<= 1) {
                float t0 = __shfl_up(v0, o);
                float t1 = __shfl_up(v1, o);
                float t2 = __shfl_up(v2, o);
                if (lane >= o) { v0 += t0; v1 += t1; v2 += t2; }
            }
            float c1 = __shfl(v0, 62 + (lane & 1)); v1 += c1;
            float c2 = __shfl(v1, 62 + (lane & 1)); v2 += c2;
            float* outp = Sw + ch * 162;
            if (lane < 2) outp[lane] = 0.f;
            outp[lane + 2]  = v0;
            outp[lane + 66] = v1;
            if (lane < 32) outp[lane + 130] = v2;
        }
#pragma unroll
        for (int t = lane; t < N; t += 64) {
            int lo = t * S, hi = lo + 2 * K;
            float a0 = Sw[0 * 162 + hi] - Sw[0 * 162 + lo];
            float a1 = Sw[1 * 162 + hi] - Sw[1 * 162 + lo];
            float a2 = Sw[2 * 162 + hi] - Sw[2 * 162 + lo];
            float a3 = Sw[3 * 162 + hi] - Sw[3 * 162 + lo];
            float a4 = Sw[4 * 162 + hi] - Sw[4 * 162 + lo];
            float xm = a0 / numel, ym = a1 / numel;
            float cross = a4 - ym * a0 - xm * a1 + ym * xm * numel;
            float xvar  = a2 - 2.f * xm * a0 + xm * xm * numel;
            float yvar  = a3 - 2.f * ym * a1 + ym * ym * numel;
            v += cross * cross / (xvar * yvar + 1e-5f);
        }
    }
    for (int o = 32; o > 0; o >>= 1) v += __shfl_down(v, o, 64);
    if (lane == 0) wsum[wid] = v;
    __syncthreads();
    if (threadIdx.x == 0) atomicAdd(acc, wsum[0] + wsum[1] + wsum[2] + wsum[3]);
}

__global__ void finalize_kernel(const float* __restrict__ acc, float* __restrict__ out,
                                float c0, float c1, float c2,
                                float w0, float w1, float w2) {
    if (threadIdx.x == 0 && blockIdx.x == 0) {
        out[0] = w0 * (1.f - acc[0] / c0) +
                 w1 * (1.f - acc[1] / c1) +
                 w2 * (1.f - acc[2] / c2);
    }
}

// ---- per-scale launcher ----
template<int N, int K, int S, int NCH, int CL1, int CL2>
static void run_scale(const float* ip, const float* tp, float* xb, float* yb,
                      float* acc, int B, hipStream_t stream) {
    constexpr int NPC0 = (N + NCH - 1) / NCH;
    constexpr int CC1  = (NPC0 + CL1 - 1) / CL1;
    constexpr int CC2  = (NPC0 + CL2 - 1) / CL2;
    const long P  = (long)B * DD * DD;
    const long t1 = P * NCH * CC1;
    k1t<N, K, S, NCH, CL1><<<dim3((unsigned)((t1 + 255) / 256)), dim3(256), 0, stream>>>(
        ip, tp, xb, B);
    const long Q  = 5L * B * N * DD;
    const long t2 = Q * NCH * CC2;
    k2t<N, K, S, NCH, CL2><<<dim3((unsigned)((t2 + 255) / 256)), dim3(256), 0, stream>>>(
        xb, yb, B);
    const long R3 = (long)B * N * N;
    k3t<N, K, S><<<dim3((unsigned)((R3 + 3) / 4)), dim3(256), 0, stream>>>(yb, acc, B);
}

extern "C" void kernel_launch(void* const* d_in, const int* in_sizes, int n_in,
                              void* d_out, int out_size, void* d_ws, size_t ws_size,
                              hipStream_t stream) {
    const float* input  = (const float*)d_in[0];
    const float* target = (const float*)d_in[1];
    float* out = (float*)d_out;

    char* ws = (char*)d_ws;
    float* acc = (float*)ws;
    const size_t accPad = 256;

    const size_t xbF = 5ull * 2 * 71 * DD * DD;     // scale-0 max
    const size_t ybF = 5ull * 2 * 71 * 71 * DD;
    const size_t fullNeed = accPad + (xbF + ybF) * sizeof(float);   // ~105 MB
    const int NB = (ws_size >= fullNeed) ? 2 : 1;

    float* xb = (float*)(ws + accPad);
    float* yb = xb + 5ull * NB * 71 * DD * DD;

    hipMemsetAsync(acc, 0, 3 * sizeof(float), stream);

    for (int b0 = 0; b0 < 2; b0 += NB) {
        const float* ip = input  + (size_t)b0 * DD * DD * DD;
        const float* tp = target + (size_t)b0 * DD * DD * DD;
        run_scale<71, 10,  2, 1, 12, 12>(ip, tp, xb, yb, acc + 0, NB, stream);
        run_scale<25, 20,  5, 2,  7,  7>(ip, tp, xb, yb, acc + 1, NB, stream);
        run_scale< 9, 40, 10, 1,  5,  3>(ip, tp, xb, yb, acc + 2, NB, stream);
    }
    finalize_kernel<<<dim3(1), dim3(64), 0, stream>>>(
        acc, out,
        2.f * 71.f * 71.f * 71.f,
        2.f * 25.f * 25.f * 25.f,
        2.f * 9.f * 9.f * 9.f,
        0.1f, 0.3f, 0.6f);
}